// Round 1
// baseline (258.185 us; speedup 1.0000x reference)
//
#include <hip/hip_runtime.h>

typedef __bf16 bf16;
typedef __attribute__((ext_vector_type(4))) float f32x4;
typedef __attribute__((ext_vector_type(8))) bf16 bf16x8;
typedef __attribute__((ext_vector_type(4))) bf16 bf16x4;
typedef __attribute__((ext_vector_type(4))) unsigned int u32x4;

constexpr int Bc = 4, Sc = 1024, Dc = 1024, Hc = 16, DKc = 64;

// ---------------- helpers ----------------

// Stage a 64x64 bf16 tile (row-major, leading dim `ld`) into swizzled LDS.
// Swizzle: element = r*64 + (c ^ ((r&7)<<3))  (== byte ^ ((r&7)<<4), 16B granules)
__device__ __forceinline__ void stage_tile(bf16* s, const bf16* g, int ld) {
  const int t = threadIdx.x;
#pragma unroll
  for (int i = 0; i < 2; ++i) {
    const int G = t + i * 256;            // granule id 0..511, 8 bf16 each
    const int r = G >> 3, gr = G & 7;
    const u32x4 v = *(const u32x4*)(g + (long)r * ld + gr * 8);
    *(u32x4*)(s + r * 64 + ((gr * 8) ^ ((r & 7) << 3))) = v;
  }
}

// Load one MFMA operand fragment (16x16x32 bf16) from a swizzled 64x64 LDS tile.
// row: tile row this lane contributes (m for A, n for BT). kofs: 0 or 32.
// Identical gather for A and BT => any consistent k-permutation is correct.
__device__ __forceinline__ bf16x8 frag_ld(const bf16* s, int row, int kofs) {
  const int lane = threadIdx.x & 63;
  const int c0 = kofs + (((lane >> 4) & 3) << 2);
  const int sw = (row & 7) << 3;
  union { bf16x8 v8; bf16x4 v4[2]; } u;
  u.v4[0] = *(const bf16x4*)(s + row * 64 + (c0 ^ sw));
  u.v4[1] = *(const bf16x4*)(s + row * 64 + ((c0 + 16) ^ sw));
  return u.v8;
}

// ---------------- conversion / transpose ----------------

__global__ __launch_bounds__(256) void convert_kernel(const float* __restrict__ in,
                                                      bf16* __restrict__ out) {
  const int i = blockIdx.x * 256 + threadIdx.x;   // group of 4
  const f32x4 v = ((const f32x4*)in)[i];
  bf16x4 o;
  o[0] = (bf16)v[0]; o[1] = (bf16)v[1]; o[2] = (bf16)v[2]; o[3] = (bf16)v[3];
  ((bf16x4*)out)[i] = o;
}

__global__ __launch_bounds__(256) void transpose_weights(
    const float* __restrict__ Wq, const float* __restrict__ Wk,
    const float* __restrict__ Wv, const float* __restrict__ Wc,
    bf16* __restrict__ WqT, bf16* __restrict__ WkT,
    bf16* __restrict__ WvT, bf16* __restrict__ WcT) {
  const int i = blockIdx.x * 256 + threadIdx.x;
  if (i < 1048576) {                       // WqT[h][dk][d] = Wq[h][d][dk]
    const int h = i >> 16, r = i & 65535, dk = r >> 10, d = r & 1023;
    WqT[i] = (bf16)Wq[(h << 16) + d * 64 + dk];
  } else if (i < 1114112) {                // WkT[dk][d]
    const int j = i - 1048576, dk = j >> 10, d = j & 1023;
    WkT[j] = (bf16)Wk[d * 64 + dk];
  } else if (i < 1179648) {                // WvT[dk][d]
    const int j = i - 1114112, dk = j >> 10, d = j & 1023;
    WvT[j] = (bf16)Wv[d * 64 + dk];
  } else if (i < 1245184) {                // WcT[dk][hdk]
    const int j = i - 1179648, dk = j >> 10, c = j & 1023;
    WcT[j] = (bf16)Wc[c * 64 + dk];
  }
}

// ---------------- generic NT GEMM: C[m][n] = A[m][:K] . BT[n][:K] + bias ----------------
// flags bit0: fp32 output (else bf16). bit1: bias indexed by m (else by n).
__global__ __launch_bounds__(256) void gemm_nt(
    const bf16* __restrict__ Ab, const bf16* __restrict__ BTb,
    void* __restrict__ Cb, const float* __restrict__ biasb,
    int K, int ldA, int ldBT, int ldC,
    long aZ, int aZdiv, long bZ, int bZmod, long cZ,
    int biasZ, int biasZmod, int flags) {
  const int z = blockIdx.z;
  const bf16* A  = Ab  + (long)(z / aZdiv) * aZ;
  const bf16* BT = BTb + (long)(z % bZmod) * bZ;
  const float* bias = biasb + (long)(z % biasZmod) * biasZ;
  char* C = (char*)Cb + (long)z * cZ * ((flags & 1) ? 4 : 2);
  const int m0 = blockIdx.x * 64, n0 = blockIdx.y * 64;

  __shared__ bf16 sA[4096];
  __shared__ bf16 sB[4096];

  const int lane = threadIdx.x & 63;
  const int w = threadIdx.x >> 6;

  f32x4 acc[4];
#pragma unroll
  for (int nb = 0; nb < 4; ++nb) acc[nb] = (f32x4){0.f, 0.f, 0.f, 0.f};

  for (int kk = 0; kk < K; kk += 64) {
    __syncthreads();
    stage_tile(sA, A + (long)m0 * ldA + kk, ldA);
    stage_tile(sB, BT + (long)n0 * ldBT + kk, ldBT);
    __syncthreads();
#pragma unroll
    for (int ks = 0; ks < 2; ++ks) {
      const bf16x8 af = frag_ld(sA, 16 * w + (lane & 15), ks * 32);
#pragma unroll
      for (int nb = 0; nb < 4; ++nb) {
        const bf16x8 bfr = frag_ld(sB, nb * 16 + (lane & 15), ks * 32);
        acc[nb] = __builtin_amdgcn_mfma_f32_16x16x32_bf16(af, bfr, acc[nb], 0, 0, 0);
      }
    }
  }

  const int rbase = m0 + 16 * w + ((lane >> 4) << 2);
#pragma unroll
  for (int nb = 0; nb < 4; ++nb) {
    const int col = n0 + nb * 16 + (lane & 15);
    const float bn = (flags & 2) ? 0.f : bias[col];
#pragma unroll
    for (int r = 0; r < 4; ++r) {
      const int row = rbase + r;
      const float v = acc[nb][r] + ((flags & 2) ? bias[row] : bn);
      if (flags & 1) ((float*)C)[(long)row * ldC + col] = v;
      else           ((bf16*)C)[(long)row * ldC + col] = (bf16)v;
    }
  }
}

// ---------------- fused attention ----------------
// Per block: one (b,h), 64 query rows. Two passes (recompute scores), no max
// subtraction (scores ~N(0,1): exp is fp32-safe). Writes fp32 attn + bf16 concat.
__global__ __launch_bounds__(256) void attn_kernel(
    const bf16* __restrict__ qproj, const bf16* __restrict__ kproj,
    const bf16* __restrict__ vT, float* __restrict__ attn_out,
    bf16* __restrict__ concat) {
  const int s0 = blockIdx.x * 64;
  const int h = blockIdx.y, b = blockIdx.z;
  const int lane = threadIdx.x & 63;
  const int w = threadIdx.x >> 6;
  const float scale = 0.125f;

  __shared__ bf16 sQ[4096];
  __shared__ bf16 sK[4096];
  __shared__ bf16 sV[4096];
  __shared__ bf16 sP[4096];

  const bf16* qp = qproj + ((long)(b * Hc + h) * Sc + s0) * DKc;
  const bf16* kp = kproj + (long)b * Sc * DKc;
  const bf16* vp = vT + (long)b * DKc * Sc;
  float* ao = attn_out + ((long)(b * Hc + h) * Sc + s0) * Sc;
  bf16* co = concat + (long)(b * Sc + s0) * (Hc * DKc) + h * DKc;

  stage_tile(sQ, qp, DKc);

  float lsum[4] = {0.f, 0.f, 0.f, 0.f};

  // ---- pass A: row sums of exp(scores) ----
  for (int tc = 0; tc < 16; ++tc) {
    __syncthreads();
    stage_tile(sK, kp + tc * 64 * DKc, DKc);
    __syncthreads();
    f32x4 sc[4];
#pragma unroll
    for (int nb = 0; nb < 4; ++nb) sc[nb] = (f32x4){0.f, 0.f, 0.f, 0.f};
#pragma unroll
    for (int ks = 0; ks < 2; ++ks) {
      const bf16x8 af = frag_ld(sQ, 16 * w + (lane & 15), ks * 32);
#pragma unroll
      for (int nb = 0; nb < 4; ++nb) {
        const bf16x8 bfr = frag_ld(sK, nb * 16 + (lane & 15), ks * 32);
        sc[nb] = __builtin_amdgcn_mfma_f32_16x16x32_bf16(af, bfr, sc[nb], 0, 0, 0);
      }
    }
#pragma unroll
    for (int nb = 0; nb < 4; ++nb)
#pragma unroll
      for (int r = 0; r < 4; ++r) lsum[r] += __expf(sc[nb][r] * scale);
  }
  // reduce across the 16 lanes of each quarter-group (cols) -> full row sums
#pragma unroll
  for (int off = 1; off < 16; off <<= 1)
#pragma unroll
    for (int r = 0; r < 4; ++r) lsum[r] += __shfl_xor(lsum[r], off, 64);
  float invl[4];
#pragma unroll
  for (int r = 0; r < 4; ++r) invl[r] = 1.f / lsum[r];

  f32x4 oacc[4];
#pragma unroll
  for (int nb = 0; nb < 4; ++nb) oacc[nb] = (f32x4){0.f, 0.f, 0.f, 0.f};

  // ---- pass B: recompute scores, write attn, PV ----
  for (int tc = 0; tc < 16; ++tc) {
    __syncthreads();                       // prev MFMA done with sK/sP/sV
    stage_tile(sK, kp + tc * 64 * DKc, DKc);
    __syncthreads();
    f32x4 sc[4];
#pragma unroll
    for (int nb = 0; nb < 4; ++nb) sc[nb] = (f32x4){0.f, 0.f, 0.f, 0.f};
#pragma unroll
    for (int ks = 0; ks < 2; ++ks) {
      const bf16x8 af = frag_ld(sQ, 16 * w + (lane & 15), ks * 32);
#pragma unroll
      for (int nb = 0; nb < 4; ++nb) {
        const bf16x8 bfr = frag_ld(sK, nb * 16 + (lane & 15), ks * 32);
        sc[nb] = __builtin_amdgcn_mfma_f32_16x16x32_bf16(af, bfr, sc[nb], 0, 0, 0);
      }
    }
    // exp, attn write (normalized), P -> LDS (unnormalized bf16)
#pragma unroll
    for (int nb = 0; nb < 4; ++nb) {
#pragma unroll
      for (int r = 0; r < 4; ++r) {
        const float p = __expf(sc[nb][r] * scale);
        const int row = 16 * w + ((lane >> 4) << 2) + r;    // s-local
        const int col = nb * 16 + (lane & 15);              // t-local
        ao[(long)row * Sc + tc * 64 + col] = p * invl[r];
        sP[row * 64 + (col ^ ((row & 7) << 3))] = (bf16)p;
      }
    }
    stage_tile(sV, vp + tc * 64, Sc);      // rows = dk, cols = t-chunk
    __syncthreads();
#pragma unroll
    for (int ks = 0; ks < 2; ++ks) {
      const bf16x8 pf = frag_ld(sP, 16 * w + (lane & 15), ks * 32);
#pragma unroll
      for (int nb = 0; nb < 4; ++nb) {
        const bf16x8 vf = frag_ld(sV, nb * 16 + (lane & 15), ks * 32);
        oacc[nb] = __builtin_amdgcn_mfma_f32_16x16x32_bf16(pf, vf, oacc[nb], 0, 0, 0);
      }
    }
  }

  // epilogue: normalize PV, store concat slice
#pragma unroll
  for (int nb = 0; nb < 4; ++nb) {
#pragma unroll
    for (int r = 0; r < 4; ++r) {
      const int row = 16 * w + ((lane >> 4) << 2) + r;
      const int col = nb * 16 + (lane & 15);
      co[(long)row * (Hc * DKc) + col] = (bf16)(oacc[nb][r] * invl[r]);
    }
  }
}

// ---------------- launcher ----------------

extern "C" void kernel_launch(void* const* d_in, const int* in_sizes, int n_in,
                              void* d_out, int out_size, void* d_ws, size_t ws_size,
                              hipStream_t stream) {
  const float* query = (const float*)d_in[0];
  const float* key   = (const float*)d_in[1];
  const float* value = (const float*)d_in[2];
  const float* Wq = (const float*)d_in[3];
  const float* bq = (const float*)d_in[4];
  const float* Wk = (const float*)d_in[5];
  const float* bk = (const float*)d_in[6];
  const float* Wv = (const float*)d_in[7];
  const float* bv = (const float*)d_in[8];
  const float* Wc = (const float*)d_in[9];
  const float* bc = (const float*)d_in[10];

  bf16* qbf    = (bf16*)d_ws;              // [B][S][D]      4M
  bf16* kbf    = qbf + 4194304;            // 4M
  bf16* vbf    = kbf + 4194304;            // 4M
  bf16* WqT    = vbf + 4194304;            // [H][DK][D]     1M
  bf16* WkT    = WqT + 1048576;            // [DK][D]        64K
  bf16* WvT    = WkT + 65536;              // 64K
  bf16* WcT    = WvT + 65536;              // [DK][H*DK]     64K
  bf16* q_proj = WcT + 65536;              // [B][H][S][DK]  4M
  bf16* k_proj = q_proj + 4194304;         // [B][S][DK]     256K
  bf16* vTp    = k_proj + 262144;          // [B][DK][S]     256K
  bf16* concat = vTp + 262144;             // [B][S][H*DK]   4M

  float* out0 = (float*)d_out;                       // [B][S][DK]
  float* attn = out0 + (long)Bc * Sc * DKc;          // [B][H][S][S]

  convert_kernel<<<4096, 256, 0, stream>>>(query, qbf);
  convert_kernel<<<4096, 256, 0, stream>>>(key, kbf);
  convert_kernel<<<4096, 256, 0, stream>>>(value, vbf);
  transpose_weights<<<4864, 256, 0, stream>>>(Wq, Wk, Wv, Wc, WqT, WkT, WvT, WcT);

  // q_proj: per (b,h): qbf[b] @ WqT[h]^T -> [S][DK]
  gemm_nt<<<dim3(16, 1, 64), 256, 0, stream>>>(
      qbf, WqT, q_proj, bq, 1024, 1024, 1024, 64,
      (long)Sc * Dc, 16, (long)DKc * Dc, 16, (long)Sc * DKc, DKc, 16, 0);
  // k_proj: per b: kbf[b] @ WkT^T -> [S][DK]
  gemm_nt<<<dim3(16, 1, 4), 256, 0, stream>>>(
      kbf, WkT, k_proj, bk, 1024, 1024, 1024, 64,
      (long)Sc * Dc, 1, 0L, 1, (long)Sc * DKc, 0, 1, 0);
  // vT: per b: WvT @ vbf[b]^T -> [DK][S], bias per-m
  gemm_nt<<<dim3(1, 16, 4), 256, 0, stream>>>(
      WvT, vbf, vTp, bv, 1024, 1024, 1024, 1024,
      0L, 1, (long)Sc * Dc, 4, (long)DKc * Sc, 0, 1, 2);

  attn_kernel<<<dim3(16, 16, 4), 256, 0, stream>>>(q_proj, k_proj, vTp, attn, concat);

  // combine: per b: concat[b] @ WcT^T + bc -> fp32 out
  gemm_nt<<<dim3(16, 1, 4), 256, 0, stream>>>(
      concat, WcT, out0, bc, 1024, 1024, 1024, 64,
      (long)Sc * Dc, 1, 0L, 1, (long)Sc * DKc, 0, 1, 1);
}